// Round 19
// baseline (90.789 us; speedup 1.0000x reference)
//
#include <hip/hip_runtime.h>

typedef unsigned short u16;
typedef unsigned int   u32;
typedef __attribute__((ext_vector_type(8))) short bf16x8;
typedef __attribute__((ext_vector_type(4))) float f32x4;
typedef __attribute__((ext_vector_type(4))) u32   u32x4;

#define MFMA(a,b,c) __builtin_amdgcn_mfma_f32_16x16x32_bf16(a,b,c,0,0,0)

// B=4, S=1024, E=1024, H=16, D=64; M = B*S = 4096.

__device__ __forceinline__ u32 cvtpk(float lo, float hi){
  u32 r; asm("v_cvt_pk_bf16_f32 %0, %1, %2" : "=v"(r) : "v"(lo), "v"(hi)); return r;
}
__device__ __forceinline__ u16 f2bf(float f){ return (u16)cvtpk(f,f); }
__device__ __forceinline__ bf16x8 cvt8(f32x4 lo, f32x4 hi){
  u32x4 u;
  u.x = cvtpk(lo[0],lo[1]); u.y = cvtpk(lo[2],lo[3]);
  u.z = cvtpk(hi[0],hi[1]); u.w = cvtpk(hi[2],hi[3]);
  return *(bf16x8*)&u;
}

// XOR swizzle for [row][64 bf16] LDS tiles (128B rows). BYTE offset.
__device__ __forceinline__ int swz(int row, int col){
  return (((row<<6) + col)<<1) ^ ((row&7)<<4);
}

// async global->LDS, 16B/lane; LDS dest wave-uniform (HW adds lane*16)
__device__ __forceinline__ void gl16(const void* g, void* l){
  __builtin_amdgcn_global_load_lds(
      (const __attribute__((address_space(1))) u32*)g,
      (__attribute__((address_space(3))) u32*)l, 16, 0, 0);
}

// stage ROWSx64 bf16 tile via global_load_lds; source-side swizzle ^(row&7).
template<int ROWS>
__device__ __forceinline__ void stage_bf16(const u16* g, size_t ldg, char* lds, int wv, int lane){
  #pragma unroll
  for (int i=0;i<ROWS/32;++i){
    const int r0 = wv*(ROWS/4) + (i<<3);
    const int row = r0 + (lane>>3);
    const int c = ((lane&7) ^ (row&7)) << 3;
    gl16(g + (size_t)row*ldg + c, lds + (r0<<7));
  }
}

__device__ __forceinline__ bf16x8 frag_bf16(const char* lds, int row, int kcol){
  return *(const bf16x8*)(lds + swz(row,kcol));
}

// ---------------- cvtx + mask-compaction fused ----------------
__global__ __launch_bounds__(256) void prep_k(
    const float* __restrict__ wq, const float* __restrict__ wk, const float* __restrict__ wo,
    const float* __restrict__ q,  const float* __restrict__ k,  const float* __restrict__ v,
    u16* __restrict__ out,
    const int* __restrict__ mask, int* __restrict__ gidx, int* __restrict__ cnts)
{
  const int tid = threadIdx.x;
  if (blockIdx.x < 7680){
    const size_t i8 = (((size_t)blockIdx.x<<8) + tid) << 3;
    const float* src;
    if      (i8 <  1048576u) src = wq + i8;
    else if (i8 <  2097152u) src = wk + (i8 - 1048576u);
    else if (i8 <  3145728u) src = wo + (i8 - 2097152u);
    else if (i8 <  7340032u) src = q  + (i8 - 3145728u);
    else if (i8 < 11534336u){
      const size_t off = i8 - 7340032u;
      if (!mask[off>>10]) return;
      src = k + off;
    } else {
      const size_t off = i8 - 11534336u;
      if (!mask[off>>10]) return;
      src = v + off;
    }
    f32x4 lo = *(const f32x4*)src, hi = *(const f32x4*)(src+4);
    *(bf16x8*)(out + i8) = cvt8(lo, hi);
  } else {
    const int b = blockIdx.x - 7680, lane = tid&63, wv = tid>>6;
    __shared__ int wsum[4];
    int4 z4; z4.x=0; z4.y=0; z4.z=0; z4.w=0;
    *(int4*)(gidx + (b<<10) + (tid<<2)) = z4;          // init pads
    const int4 m = *(const int4*)(mask + (b<<10) + (tid<<2));
    const int c0 = (m.x!=0)+(m.y!=0)+(m.z!=0)+(m.w!=0);
    int pre = c0;
    #pragma unroll
    for (int i=1;i<64;i<<=1){
      int t = __shfl_up(pre, i);
      if (lane >= i) pre += t;
    }
    if (lane==63) wsum[wv] = pre;
    __syncthreads();
    int base = pre - c0;
    #pragma unroll
    for (int w=0;w<4;++w) if (w<wv) base += wsum[w];
    int p = base;
    const int s0 = tid<<2;
    if (m.x) gidx[(b<<10) + p++] = s0;
    if (m.y) gidx[(b<<10) + p++] = s0+1;
    if (m.z) gidx[(b<<10) + p++] = s0+2;
    if (m.w) gidx[(b<<10) + p++] = s0+3;
    if (tid==255) cnts[b] = p;
  }
}

// ---------------- projection GEMM body: 2-phase dbuf (T3-minimum), 128x128 ----------------
// Per K-step: issue next tile's gl16 into other LDS half BEFORE computing current half;
// ONE barrier per K-step (drains vmcnt for next tile + orders buffer reuse).
template<int V, bool GA, bool GB>
__device__ __forceinline__ void proj_body(
    const u16* __restrict__ Aa, const u16* __restrict__ Bb,
    const int* __restrict__ gA, const int* __restrict__ gB,
    const float* __restrict__ bias, u16* __restrict__ outb,
    char* As0, char* Bs0)
{
  const int tid = threadIdx.x, lane = tid&63, wv = tid>>6;
  const int wm = wv>>1, wn = wv&1, l15 = lane&15, g4 = lane>>4;

  int growA[4], growB[4];
  #pragma unroll
  for (int i=0;i<4;++i){
    const int row = (wv<<5)+(i<<3)+(lane>>3);
    growA[i] = GA ? (gA[row] & 1023) : row;
    growB[i] = GB ? (gB[row] & 1023) : row;
  }

  // stage tile at K-offset kt into given halves
  auto stageAB = [&](int kt, char* Ad, char* Bd){
    #pragma unroll
    for (int i=0;i<4;++i){
      const int r0 = (wv<<5)+(i<<3), row = r0+(lane>>3);
      const int c = ((lane&7)^(row&7))<<3;
      gl16(Aa + (size_t)growA[i]*1024 + kt + c, Ad + (r0<<7));
      gl16(Bb + (size_t)growB[i]*1024 + kt + c, Bd + (r0<<7));
    }
  };

  f32x4 acc[4][4] = {};

  stageAB(0, As0, Bs0);
  __syncthreads();             // tile 0 staged (vmcnt drained)

  int cb = 0;
  #pragma unroll 1
  for (int kt=0; kt<1024; kt+=64){
    char* Ac = As0 + (cb<<14);       char* Bc = Bs0 + (cb<<14);
    char* An = As0 + ((cb^1)<<14);   char* Bn = Bs0 + ((cb^1)<<14);
    if (kt < 960) stageAB(kt+64, An, Bn);   // issue-early: latency hides under MFMA

    #pragma unroll
    for (int kb=0;kb<64;kb+=32){
      const int kcol = kb + (g4<<3);
      bf16x8 af[4], bf_[4];
      #pragma unroll
      for (int t=0;t<4;++t)
        af[t] = frag_bf16(Ac, (wm<<6) + (t<<4) + l15, kcol);
      #pragma unroll
      for (int t=0;t<4;++t)
        bf_[t] = frag_bf16(Bc, (wn<<6) + (t<<4) + l15, kcol);
      #pragma unroll
      for (int mt=0;mt<4;++mt)
        #pragma unroll
        for (int nt=0;nt<4;++nt)
          acc[mt][nt] = MFMA(af[mt], bf_[nt], acc[mt][nt]);
    }
    __syncthreads();   // drains next-tile vmcnt + orders reuse of current halves
    cb ^= 1;
  }

  f32x4 bmv[4];
  if (V==1){
    #pragma unroll
    for (int mt=0;mt<4;++mt)
      bmv[mt] = *(const f32x4*)(bias + (wm<<6) + (mt<<4) + (g4<<2));
  }
  #pragma unroll
  for (int nt=0;nt<4;++nt){
    const int col = (wn<<6) + (nt<<4) + l15;
    const float bvn = (V==1) ? 0.f : bias[col];
    #pragma unroll
    for (int mt=0;mt<4;++mt){
      f32x4 a = acc[mt][nt];
      #pragma unroll
      for (int j=0;j<4;++j){
        const int ml = (wm<<6) + (mt<<4) + (g4<<2) + j;
        const float val = a[j] + ((V==1) ? bmv[mt][j] : bvn);
        if (V==1) outb[(size_t)ml*4096 + col] = f2bf(val);
        else      outb[(size_t)ml*1024 + col] = f2bf(val);
      }
    }
  }
}

// ---------------- all three projections in ONE launch (768 blocks, all 128x128) ----------
__global__ __launch_bounds__(256,2) void proj_k(
    const u16* __restrict__ qb, const u16* __restrict__ kb, const u16* __restrict__ vb,
    const u16* __restrict__ wqb, const u16* __restrict__ wkb,
    const float* __restrict__ bq, const float* __restrict__ bk,
    u16* __restrict__ qp, u16* __restrict__ kp, u16* __restrict__ vt,
    const int* __restrict__ gidx, const int* __restrict__ cnts)
{
  __shared__ __align__(16) char As[2][16384];
  __shared__ __align__(16) char Bs[2][16384];
  const int bid = blockIdx.x;
  if (bid < 256){
    const int m0 = (bid&31)<<7, n0 = ((bid>>5)&7)<<7;
    proj_body<0,false,false>(qb + (size_t)m0*1024, wqb + (size_t)n0*1024, nullptr, nullptr,
                             bq + n0, qp + (size_t)m0*1024 + n0, As[0], Bs[0]);
  } else if (bid < 512){
    const int local = bid-256;
    const int m0 = (local&31)<<7, n0 = ((local>>5)&7)<<7;
    const int b = m0>>10, mloc = m0&1023;
    if (mloc >= cnts[b]) return;
    proj_body<0,true,false>(kb + ((size_t)(b<<10))*1024, wkb + (size_t)n0*1024,
                            gidx + (b<<10) + mloc, nullptr,
                            bk + n0, kp + ((size_t)((b<<10)+mloc))*1024 + n0, As[0], Bs[0]);
  } else {
    const int local = bid-512;
    const int m0 = (local&7)<<7, n0 = (local>>3)<<7;
    const int b = n0>>10, nloc = n0&1023;
    if (nloc >= cnts[b]) return;
    proj_body<1,false,true>(wkb + (size_t)m0*1024, vb + ((size_t)(b<<10))*1024,
                            nullptr, gidx + (b<<10) + nloc,
                            bk + m0, vt + (size_t)m0*4096 + (b<<10) + nloc, As[0], Bs[0]);
  }
}

// ---------------- output projection: out = ctx @ Wo^T + bo (f32 out) ----------------
__global__ __launch_bounds__(256,4) void oproj_k(
    const u16* __restrict__ ctx, const u16* __restrict__ wob,
    const float* __restrict__ bo, float* __restrict__ of)
{
  constexpr int BN = 64, NT = 2;
  __shared__ __align__(16) char As[16384];
  __shared__ __align__(16) char Bs[BN*128];
  const int m0 = blockIdx.x<<7, n0 = blockIdx.y*BN;
  const int tid = threadIdx.x, lane = tid&63, wv = tid>>6;
  const int wm = wv>>1, wn = wv&1, l15 = lane&15, g4 = lane>>4;

  f32x4 acc[4][NT] = {};

  #pragma unroll 1
  for (int kt=0; kt<1024; kt+=64){
    __syncthreads();
    stage_bf16<128>(ctx + (size_t)m0*1024 + kt, 1024, As, wv, lane);
    stage_bf16<BN> (wob + (size_t)n0*1024 + kt, 1024, Bs, wv, lane);
    __syncthreads();

    #pragma unroll
    for (int kb=0;kb<64;kb+=32){
      const int kcol = kb + (g4<<3);
      bf16x8 af[4], bf_[NT];
      #pragma unroll
      for (int t=0;t<4;++t)
        af[t] = frag_bf16(As, (wm<<6) + (t<<4) + l15, kcol);
      #pragma unroll
      for (int t=0;t<NT;++t)
        bf_[t] = frag_bf16(Bs, wn*(BN>>1) + (t<<4) + l15, kcol);
      #pragma unroll
      for (int mt=0;mt<4;++mt)
        #pragma unroll
        for (int nt=0;nt<NT;++nt)
          acc[mt][nt] = MFMA(af[mt], bf_[nt], acc[mt][nt]);
    }
  }

  #pragma unroll
  for (int nt=0;nt<NT;++nt){
    const int col = n0 + wn*(BN>>1) + (nt<<4) + l15;
    const float bvn = bo[col];
    #pragma unroll
    for (int mt=0;mt<4;++mt){
      const int mb = m0 + (wm<<6) + (mt<<4) + (g4<<2);
      f32x4 a = acc[mt][nt];
      #pragma unroll
      for (int j=0;j<4;++j)
        of[(size_t)(mb+j)*1024 + col] = a[j] + bvn;
    }
  }
}

// ---------------- flash attention over COMPACTED keys (round-16 best config) -----------
// Single-buffer K/V, 48KB LDS, QBLK=128, 512 blocks.
__global__ __launch_bounds__(256) void attn_k(
    const u16* __restrict__ qp, const u16* __restrict__ kp, const u16* __restrict__ vt,
    const int* __restrict__ cnts, u16* __restrict__ ctx)
{
  const int bid = blockIdx.x;
  const int wg  = (bid&7)*64 + (bid>>3);     // XCD-chunked (512 = 8*64, bijective)
  const int qt = wg&7, h = (wg>>3)&15, b = wg>>7;

  __shared__ __align__(16) u16 Qs[128*64];    // 16KB
  __shared__ __align__(16) u16 Ks[64*64];     // 8KB
  __shared__ __align__(16) u16 Vs[64*64];     // 8KB (rows=d, cols=key)
  __shared__ __align__(16) u16 Ps[4*32*64];   // 16KB per-wave P

  const int tid = threadIdx.x, lane = tid&63, wv = tid>>6;
  const int hc = h<<6, l15 = lane&15;
  const float C2 = 0.18033688011112042f;      // 0.125 * log2(e)

  const int cnt = cnts[b];
  const int ntiles = (cnt + 63) >> 6;

  { // stage Q (128 x 64)
    const u16* Qg = qp + ((size_t)((b<<10) + (qt<<7)))*1024 + hc;
    #pragma unroll
    for (int i=0;i<4;++i){
      const int r0 = (wv<<5) + (i<<3);
      const int row = r0 + (lane>>3);
      const int c = ((lane&7) ^ (row&7)) << 3;
      gl16(Qg + (size_t)row*1024 + c, (char*)Qs + (r0<<7));
    }
  }

  const u16* Kg = kp + ((size_t)(b<<10))*1024 + hc;
  const u16* Vg = vt + ((size_t)hc)*4096 + (b<<10);

  f32x4 o[2][4] = {};
  float lr[2][4] = {};
  u16* Pw = Ps + (wv<<11);

  #pragma unroll 1
  for (int kt=0; kt<ntiles; ++kt){
    __syncthreads();   // previous tile's compute done -> safe to overwrite K/V
    { // stage K/V tile kt (single buffer)
      #pragma unroll
      for (int i=0;i<2;++i){
        const int r0 = (wv<<4) + (i<<3);
        const int row = r0 + (lane>>3);
        const int c = ((lane&7) ^ (row&7)) << 3;
        gl16(Kg + (size_t)((kt<<6) + row)*1024 + c, (char*)Ks + (r0<<7));
        gl16(Vg + (size_t)row*4096 + (kt<<6) + c,  (char*)Vs + (r0<<7));
      }
    }
    __syncthreads();   // staged (compiler drains vmcnt; covers Q on first iter)

    // S = Q K^T  (2 q-subtiles x 4 key-subtiles)
    f32x4 sc[2][4] = {};
    #pragma unroll
    for (int kb=0;kb<64;kb+=32){
      const int kcol = kb + ((lane>>4)<<3);
      bf16x8 kf[4];
      #pragma unroll
      for (int nt=0;nt<4;++nt) kf[nt] = frag_bf16((const char*)Ks, (nt<<4)+l15, kcol);
      bf16x8 aq0 = frag_bf16((const char*)Qs, (wv<<5)+l15, kcol);
      bf16x8 aq1 = frag_bf16((const char*)Qs, (wv<<5)+16+l15, kcol);
      __builtin_amdgcn_s_setprio(1);
      #pragma unroll
      for (int nt=0;nt<4;++nt) sc[0][nt] = MFMA(aq0, kf[nt], sc[0][nt]);
      #pragma unroll
      for (int nt=0;nt<4;++nt) sc[1][nt] = MFMA(aq1, kf[nt], sc[1][nt]);
      __builtin_amdgcn_s_setprio(0);
    }

    // p = exp2(s*C2 + tailbias); slots >= cnt -> exact 0
    float bv4[4];
    #pragma unroll
    for (int nt=0;nt<4;++nt)
      bv4[nt] = ((kt<<6)+(nt<<4)+l15 < cnt) ? 0.f : -1e30f;
    #pragma unroll
    for (int sub=0;sub<2;++sub)
      #pragma unroll
      for (int nt=0;nt<4;++nt){
        f32x4 s = sc[sub][nt];
        #pragma unroll
        for (int j=0;j<4;++j){
          const float p = __builtin_amdgcn_exp2f(fmaf(s[j], C2, bv4[nt]));
          lr[sub][j] += p;
          *(u16*)((char*)Pw + swz((sub<<4)+((lane>>4)<<2)+j, (nt<<4)+l15)) = f2bf(p);
        }
      }
    asm volatile("s_waitcnt lgkmcnt(0)" ::: "memory");
    __builtin_amdgcn_sched_barrier(0);

    // O += P V
    #pragma unroll
    for (int kb=0;kb<64;kb+=32){
      const int kcol = kb + ((lane>>4)<<3);
      bf16x8 vf[4];
      #pragma unroll
      for (int nt=0;nt<4;++nt) vf[nt] = frag_bf16((const char*)Vs, (nt<<4)+l15, kcol);
      bf16x8 pa0 = frag_bf16((const char*)Pw, l15, kcol);
      bf16x8 pa1 = frag_bf16((const char*)Pw, 16+l15, kcol);
      __builtin_amdgcn_s_setprio(1);
      #pragma unroll
      for (int nt=0;nt<4;++nt) o[0][nt] = MFMA(pa0, vf[nt], o[0][nt]);
      #pragma unroll
      for (int nt=0;nt<4;++nt) o[1][nt] = MFMA(pa1, vf[nt], o[1][nt]);
      __builtin_amdgcn_s_setprio(0);
    }
  }

  // epilogue: deferred row-sum reduce, normalize, write
  #pragma unroll
  for (int sub=0;sub<2;++sub)
    #pragma unroll
    for (int j=0;j<4;++j){
      float s = lr[sub][j];
      s += __shfl_xor(s,1); s += __shfl_xor(s,2);
      s += __shfl_xor(s,4); s += __shfl_xor(s,8);
      const float inv = 1.f / fmaxf(s, 1e-30f);
      const int row = (qt<<7) + (wv<<5) + (sub<<4) + ((lane>>4)<<2) + j;
      u16* crow = ctx + ((size_t)((b<<10)+row))*1024 + hc;
      #pragma unroll
      for (int nt=0;nt<4;++nt)
        crow[(nt<<4)+l15] = f2bf(o[sub][nt][j]*inv);
    }
}

extern "C" void kernel_launch(void* const* d_in, const int* in_sizes, int n_in,
                              void* d_out, int out_size, void* d_ws, size_t ws_size,
                              hipStream_t stream) {
  const float* q    = (const float*)d_in[0];
  const float* k    = (const float*)d_in[1];
  const float* v    = (const float*)d_in[2];
  const int*   mask = (const int*)  d_in[3];
  const float* Wq   = (const float*)d_in[4];
  const float* bq   = (const float*)d_in[5];
  const float* Wk   = (const float*)d_in[6];
  const float* bk   = (const float*)d_in[7];
  const float* Wo   = (const float*)d_in[8];
  const float* bo   = (const float*)d_in[9];
  float* out = (float*)d_out;

  // ws layout: wqb 2M | wkb 2M | wob 2M | qb 8M | kb 8M | vb 8M | qp 8M | kp 8M
  //            | vt 8M | ctx 8M | gidx 16K | cnts
  char* ws = (char*)d_ws;
  u16* wqb  = (u16*)(ws);
  u16* wkb  = (u16*)(ws +  2097152);
  u16* wob  = (u16*)(ws +  4194304);
  u16* qb   = (u16*)(ws +  6291456);
  u16* kb   = (u16*)(ws + 14680064);
  u16* vb   = (u16*)(ws + 23068672);
  u16* qp   = (u16*)(ws + 31457280);
  u16* kp   = (u16*)(ws + 39845888);
  u16* vtb  = (u16*)(ws + 48234496);
  u16* ctxb = (u16*)(ws + 56623104);
  int* gidx = (int*)(ws + 65011712);
  int* cnts = (int*)(ws + 65028096);

  dim3 blk(256);
  prep_k<<<7684, blk, 0, stream>>>(Wq, Wk, Wo, q, k, v, wqb, mask, gidx, cnts);
  proj_k<<<768, blk, 0, stream>>>(qb, kb, vb, wqb, wkb, bq, bk, qp, kp, vtb, gidx, cnts);
  attn_k<<<512, blk, 0, stream>>>(qp, kp, vtb, cnts, ctxb);
  oproj_k<<<dim3(32,16), blk, 0, stream>>>(ctxb, wob, bo, out);
}

// Round 20
// 81.799 us; speedup vs baseline: 1.1099x; 1.1099x over previous
//
#include <hip/hip_runtime.h>

typedef unsigned short u16;
typedef unsigned int   u32;
typedef __attribute__((ext_vector_type(8))) short bf16x8;
typedef __attribute__((ext_vector_type(4))) float f32x4;
typedef __attribute__((ext_vector_type(4))) u32   u32x4;

#define MFMA(a,b,c) __builtin_amdgcn_mfma_f32_16x16x32_bf16(a,b,c,0,0,0)

// B=4, S=1024, E=1024, H=16, D=64; M = B*S = 4096.

__device__ __forceinline__ u32 cvtpk(float lo, float hi){
  u32 r; asm("v_cvt_pk_bf16_f32 %0, %1, %2" : "=v"(r) : "v"(lo), "v"(hi)); return r;
}
__device__ __forceinline__ u16 f2bf(float f){ return (u16)cvtpk(f,f); }
__device__ __forceinline__ bf16x8 cvt8(f32x4 lo, f32x4 hi){
  u32x4 u;
  u.x = cvtpk(lo[0],lo[1]); u.y = cvtpk(lo[2],lo[3]);
  u.z = cvtpk(hi[0],hi[1]); u.w = cvtpk(hi[2],hi[3]);
  return *(bf16x8*)&u;
}

// XOR swizzle for [row][64 bf16] LDS tiles (128B rows). BYTE offset.
__device__ __forceinline__ int swz(int row, int col){
  return (((row<<6) + col)<<1) ^ ((row&7)<<4);
}

// async global->LDS, 16B/lane; LDS dest wave-uniform (HW adds lane*16)
__device__ __forceinline__ void gl16(const void* g, void* l){
  __builtin_amdgcn_global_load_lds(
      (const __attribute__((address_space(1))) u32*)g,
      (__attribute__((address_space(3))) u32*)l, 16, 0, 0);
}

// stage ROWSx64 bf16 tile via global_load_lds; source-side swizzle ^(row&7).
template<int ROWS>
__device__ __forceinline__ void stage_bf16(const u16* g, size_t ldg, char* lds, int wv, int lane){
  #pragma unroll
  for (int i=0;i<ROWS/32;++i){
    const int r0 = wv*(ROWS/4) + (i<<3);
    const int row = r0 + (lane>>3);
    const int c = ((lane&7) ^ (row&7)) << 3;
    gl16(g + (size_t)row*ldg + c, lds + (r0<<7));
  }
}

__device__ __forceinline__ bf16x8 frag_bf16(const char* lds, int row, int kcol){
  return *(const bf16x8*)(lds + swz(row,kcol));
}

// ---------------- cvtx + mask-compaction fused ----------------
// blocks 0..7679: fp32->bf16 convert Wq|Wk|Wo|q|k|v -> contiguous bf16 region.
//   masked k/v rows SKIPPED (never gathered; pad-slot garbage zeroed by tail bias).
// blocks 7680..7683: per-batch prefix-sum -> gidx[b][slot]=orig row (0 pads), cnts[b].
__global__ __launch_bounds__(256) void prep_k(
    const float* __restrict__ wq, const float* __restrict__ wk, const float* __restrict__ wo,
    const float* __restrict__ q,  const float* __restrict__ k,  const float* __restrict__ v,
    u16* __restrict__ out,
    const int* __restrict__ mask, int* __restrict__ gidx, int* __restrict__ cnts)
{
  const int tid = threadIdx.x;
  if (blockIdx.x < 7680){
    const size_t i8 = (((size_t)blockIdx.x<<8) + tid) << 3;
    const float* src;
    if      (i8 <  1048576u) src = wq + i8;
    else if (i8 <  2097152u) src = wk + (i8 - 1048576u);
    else if (i8 <  3145728u) src = wo + (i8 - 2097152u);
    else if (i8 <  7340032u) src = q  + (i8 - 3145728u);
    else if (i8 < 11534336u){
      const size_t off = i8 - 7340032u;
      if (!mask[off>>10]) return;
      src = k + off;
    } else {
      const size_t off = i8 - 11534336u;
      if (!mask[off>>10]) return;
      src = v + off;
    }
    f32x4 lo = *(const f32x4*)src, hi = *(const f32x4*)(src+4);
    *(bf16x8*)(out + i8) = cvt8(lo, hi);
  } else {
    const int b = blockIdx.x - 7680, lane = tid&63, wv = tid>>6;
    __shared__ int wsum[4];
    int4 z4; z4.x=0; z4.y=0; z4.z=0; z4.w=0;
    *(int4*)(gidx + (b<<10) + (tid<<2)) = z4;          // init pads
    const int4 m = *(const int4*)(mask + (b<<10) + (tid<<2));
    const int c0 = (m.x!=0)+(m.y!=0)+(m.z!=0)+(m.w!=0);
    int pre = c0;
    #pragma unroll
    for (int i=1;i<64;i<<=1){
      int t = __shfl_up(pre, i);
      if (lane >= i) pre += t;
    }
    if (lane==63) wsum[wv] = pre;
    __syncthreads();
    int base = pre - c0;
    #pragma unroll
    for (int w=0;w<4;++w) if (w<wv) base += wsum[w];
    int p = base;
    const int s0 = tid<<2;
    if (m.x) gidx[(b<<10) + p++] = s0;
    if (m.y) gidx[(b<<10) + p++] = s0+1;
    if (m.z) gidx[(b<<10) + p++] = s0+2;
    if (m.w) gidx[(b<<10) + p++] = s0+3;
    if (tid==255) cnts[b] = p;
  }
}

// ---------------- projection GEMM body (m97 form, 128x128, optional A/B row-gather) ------
template<int V, bool GA, bool GB>
__device__ __forceinline__ void proj_body(
    const u16* __restrict__ Aa, const u16* __restrict__ Bb,
    const int* __restrict__ gA, const int* __restrict__ gB,
    const float* __restrict__ bias, u16* __restrict__ outb,
    char* As, char* Bs)
{
  const int tid = threadIdx.x, lane = tid&63, wv = tid>>6;
  const int wm = wv>>1, wn = wv&1, l15 = lane&15, g4 = lane>>4;

  int growA[4], growB[4];
  if (GA){
    #pragma unroll
    for (int i=0;i<4;++i) growA[i] = gA[(wv<<5)+(i<<3)+(lane>>3)] & 1023;
  }
  if (GB){
    #pragma unroll
    for (int i=0;i<4;++i) growB[i] = gB[(wv<<5)+(i<<3)+(lane>>3)] & 1023;
  }

  f32x4 acc[4][4] = {};

  #pragma unroll 1
  for (int kt=0; kt<1024; kt+=64){
    __syncthreads();
    #pragma unroll
    for (int i=0;i<4;++i){
      const int r0 = (wv<<5)+(i<<3), row = r0+(lane>>3);
      const int c = ((lane&7)^(row&7))<<3;
      const u16* srcA = GA ? Aa + (size_t)growA[i]*1024 + kt + c
                           : Aa + (size_t)row*1024 + kt + c;
      gl16(srcA, As + (r0<<7));
      const u16* srcB = GB ? Bb + (size_t)growB[i]*1024 + kt + c
                           : Bb + (size_t)row*1024 + kt + c;
      gl16(srcB, Bs + (r0<<7));
    }
    __syncthreads();

    #pragma unroll
    for (int kb=0;kb<64;kb+=32){
      const int kcol = kb + (g4<<3);
      bf16x8 af[4], bf_[4];
      #pragma unroll
      for (int t=0;t<4;++t)
        af[t] = frag_bf16(As, (wm<<6) + (t<<4) + l15, kcol);
      #pragma unroll
      for (int t=0;t<4;++t)
        bf_[t] = frag_bf16(Bs, (wn<<6) + (t<<4) + l15, kcol);
      #pragma unroll
      for (int mt=0;mt<4;++mt)
        #pragma unroll
        for (int nt=0;nt<4;++nt)
          acc[mt][nt] = MFMA(af[mt], bf_[nt], acc[mt][nt]);
    }
  }

  f32x4 bmv[4];
  if (V==1){
    #pragma unroll
    for (int mt=0;mt<4;++mt)
      bmv[mt] = *(const f32x4*)(bias + (wm<<6) + (mt<<4) + (g4<<2));
  }
  #pragma unroll
  for (int nt=0;nt<4;++nt){
    const int col = (wn<<6) + (nt<<4) + l15;
    const float bvn = (V==1) ? 0.f : bias[col];
    #pragma unroll
    for (int mt=0;mt<4;++mt){
      f32x4 a = acc[mt][nt];
      #pragma unroll
      for (int j=0;j<4;++j){
        const int ml = (wm<<6) + (mt<<4) + (g4<<2) + j;
        const float val = a[j] + ((V==1) ? bmv[mt][j] : bvn);
        if (V==1) outb[(size_t)ml*4096 + col] = f2bf(val);
        else      outb[(size_t)ml*1024 + col] = f2bf(val);
      }
    }
  }
}

// ---------------- all three projections in ONE launch (768 blocks, all 128x128) ----------
__global__ __launch_bounds__(256,4) void proj_k(
    const u16* __restrict__ qb, const u16* __restrict__ kb, const u16* __restrict__ vb,
    const u16* __restrict__ wqb, const u16* __restrict__ wkb,
    const float* __restrict__ bq, const float* __restrict__ bk,
    u16* __restrict__ qp, u16* __restrict__ kp, u16* __restrict__ vt,
    const int* __restrict__ gidx, const int* __restrict__ cnts)
{
  __shared__ __align__(16) char As[16384];
  __shared__ __align__(16) char Bs[16384];
  const int bid = blockIdx.x;
  if (bid < 256){
    const int m0 = (bid&31)<<7, n0 = ((bid>>5)&7)<<7;
    proj_body<0,false,false>(qb + (size_t)m0*1024, wqb + (size_t)n0*1024, nullptr, nullptr,
                             bq + n0, qp + (size_t)m0*1024 + n0, As, Bs);
  } else if (bid < 512){
    const int local = bid-256;
    const int m0 = (local&31)<<7, n0 = ((local>>5)&7)<<7;
    const int b = m0>>10, mloc = m0&1023;
    if (mloc >= cnts[b]) return;
    proj_body<0,true,false>(kb + ((size_t)(b<<10))*1024, wkb + (size_t)n0*1024,
                            gidx + (b<<10) + mloc, nullptr,
                            bk + n0, kp + ((size_t)((b<<10)+mloc))*1024 + n0, As, Bs);
  } else {
    const int local = bid-512;
    const int m0 = (local&7)<<7, n0 = (local>>3)<<7;
    const int b = n0>>10, nloc = n0&1023;
    if (nloc >= cnts[b]) return;
    proj_body<1,false,true>(wkb + (size_t)m0*1024, vb + ((size_t)(b<<10))*1024,
                            nullptr, gidx + (b<<10) + nloc,
                            bk + m0, vt + (size_t)m0*4096 + (b<<10) + nloc, As, Bs);
  }
}

// ---------------- output projection: out = ctx @ Wo^T + bo (f32 out) ----------------
__global__ __launch_bounds__(256,4) void oproj_k(
    const u16* __restrict__ ctx, const u16* __restrict__ wob,
    const float* __restrict__ bo, float* __restrict__ of)
{
  constexpr int BN = 64, NT = 2;
  __shared__ __align__(16) char As[16384];
  __shared__ __align__(16) char Bs[BN*128];
  const int m0 = blockIdx.x<<7, n0 = blockIdx.y*BN;
  const int tid = threadIdx.x, lane = tid&63, wv = tid>>6;
  const int wm = wv>>1, wn = wv&1, l15 = lane&15, g4 = lane>>4;

  f32x4 acc[4][NT] = {};

  #pragma unroll 1
  for (int kt=0; kt<1024; kt+=64){
    __syncthreads();
    stage_bf16<128>(ctx + (size_t)m0*1024 + kt, 1024, As, wv, lane);
    stage_bf16<BN> (wob + (size_t)n0*1024 + kt, 1024, Bs, wv, lane);
    __syncthreads();

    #pragma unroll
    for (int kb=0;kb<64;kb+=32){
      const int kcol = kb + (g4<<3);
      bf16x8 af[4], bf_[NT];
      #pragma unroll
      for (int t=0;t<4;++t)
        af[t] = frag_bf16(As, (wm<<6) + (t<<4) + l15, kcol);
      #pragma unroll
      for (int t=0;t<NT;++t)
        bf_[t] = frag_bf16(Bs, wn*(BN>>1) + (t<<4) + l15, kcol);
      #pragma unroll
      for (int mt=0;mt<4;++mt)
        #pragma unroll
        for (int nt=0;nt<NT;++nt)
          acc[mt][nt] = MFMA(af[mt], bf_[nt], acc[mt][nt]);
    }
  }

  #pragma unroll
  for (int nt=0;nt<NT;++nt){
    const int col = n0 + wn*(BN>>1) + (nt<<4) + l15;
    const float bvn = bo[col];
    #pragma unroll
    for (int mt=0;mt<4;++mt){
      const int mb = m0 + (wm<<6) + (mt<<4) + (g4<<2);
      f32x4 a = acc[mt][nt];
      #pragma unroll
      for (int j=0;j<4;++j)
        of[(size_t)(mb+j)*1024 + col] = a[j] + bvn;
    }
  }
}

// ---------------- flash attention over COMPACTED keys (single-buffer K/V, 48KB LDS) -----
// qp bf16 [B*S,E]; kp bf16 [B*S,E] compact rows; vt bf16 [E,B*S] compact cols.
// cnts[b] = live keys. Tail slots -> -1e30 bias (exp2 -> exact 0).
__global__ __launch_bounds__(256) void attn_k(
    const u16* __restrict__ qp, const u16* __restrict__ kp, const u16* __restrict__ vt,
    const int* __restrict__ cnts, u16* __restrict__ ctx)
{
  const int bid = blockIdx.x;
  const int wg  = (bid&7)*64 + (bid>>3);     // XCD-chunked (512 = 8*64, bijective)
  const int qt = wg&7, h = (wg>>3)&15, b = wg>>7;

  __shared__ __align__(16) u16 Qs[128*64];    // 16KB
  __shared__ __align__(16) u16 Ks[64*64];     // 8KB
  __shared__ __align__(16) u16 Vs[64*64];     // 8KB (rows=d, cols=key)
  __shared__ __align__(16) u16 Ps[4*32*64];   // 16KB per-wave P

  const int tid = threadIdx.x, lane = tid&63, wv = tid>>6;
  const int hc = h<<6, l15 = lane&15;
  const float C2 = 0.18033688011112042f;      // 0.125 * log2(e)

  const int cnt = cnts[b];
  const int ntiles = (cnt + 63) >> 6;

  { // stage Q (128 x 64)
    const u16* Qg = qp + ((size_t)((b<<10) + (qt<<7)))*1024 + hc;
    #pragma unroll
    for (int i=0;i<4;++i){
      const int r0 = (wv<<5) + (i<<3);
      const int row = r0 + (lane>>3);
      const int c = ((lane&7) ^ (row&7)) << 3;
      gl16(Qg + (size_t)row*1024 + c, (char*)Qs + (r0<<7));
    }
  }

  const u16* Kg = kp + ((size_t)(b<<10))*1024 + hc;
  const u16* Vg = vt + ((size_t)hc)*4096 + (b<<10);

  f32x4 o[2][4] = {};
  float lr[2][4] = {};
  u16* Pw = Ps + (wv<<11);

  #pragma unroll 1
  for (int kt=0; kt<ntiles; ++kt){
    __syncthreads();   // previous tile's compute done -> safe to overwrite K/V
    { // stage K/V tile kt (single buffer)
      #pragma unroll
      for (int i=0;i<2;++i){
        const int r0 = (wv<<4) + (i<<3);
        const int row = r0 + (lane>>3);
        const int c = ((lane&7) ^ (row&7)) << 3;
        gl16(Kg + (size_t)((kt<<6) + row)*1024 + c, (char*)Ks + (r0<<7));
        gl16(Vg + (size_t)row*4096 + (kt<<6) + c,  (char*)Vs + (r0<<7));
      }
    }
    __syncthreads();   // staged (compiler drains vmcnt; covers Q on first iter)

    // S = Q K^T  (2 q-subtiles x 4 key-subtiles)
    f32x4 sc[2][4] = {};
    #pragma unroll
    for (int kb=0;kb<64;kb+=32){
      const int kcol = kb + ((lane>>4)<<3);
      bf16x8 kf[4];
      #pragma unroll
      for (int nt=0;nt<4;++nt) kf[nt] = frag_bf16((const char*)Ks, (nt<<4)+l15, kcol);
      bf16x8 aq0 = frag_bf16((const char*)Qs, (wv<<5)+l15, kcol);
      bf16x8 aq1 = frag_bf16((const char*)Qs, (wv<<5)+16+l15, kcol);
      __builtin_amdgcn_s_setprio(1);
      #pragma unroll
      for (int nt=0;nt<4;++nt) sc[0][nt] = MFMA(aq0, kf[nt], sc[0][nt]);
      #pragma unroll
      for (int nt=0;nt<4;++nt) sc[1][nt] = MFMA(aq1, kf[nt], sc[1][nt]);
      __builtin_amdgcn_s_setprio(0);
    }

    // p = exp2(s*C2 + tailbias); slots >= cnt -> exact 0
    float bv4[4];
    #pragma unroll
    for (int nt=0;nt<4;++nt)
      bv4[nt] = ((kt<<6)+(nt<<4)+l15 < cnt) ? 0.f : -1e30f;
    #pragma unroll
    for (int sub=0;sub<2;++sub)
      #pragma unroll
      for (int nt=0;nt<4;++nt){
        f32x4 s = sc[sub][nt];
        #pragma unroll
        for (int j=0;j<4;++j){
          const float p = __builtin_amdgcn_exp2f(fmaf(s[j], C2, bv4[nt]));
          lr[sub][j] += p;
          *(u16*)((char*)Pw + swz((sub<<4)+((lane>>4)<<2)+j, (nt<<4)+l15)) = f2bf(p);
        }
      }
    asm volatile("s_waitcnt lgkmcnt(0)" ::: "memory");
    __builtin_amdgcn_sched_barrier(0);

    // O += P V
    #pragma unroll
    for (int kb=0;kb<64;kb+=32){
      const int kcol = kb + ((lane>>4)<<3);
      bf16x8 vf[4];
      #pragma unroll
      for (int nt=0;nt<4;++nt) vf[nt] = frag_bf16((const char*)Vs, (nt<<4)+l15, kcol);
      bf16x8 pa0 = frag_bf16((const char*)Pw, l15, kcol);
      bf16x8 pa1 = frag_bf16((const char*)Pw, 16+l15, kcol);
      __builtin_amdgcn_s_setprio(1);
      #pragma unroll
      for (int nt=0;nt<4;++nt) o[0][nt] = MFMA(pa0, vf[nt], o[0][nt]);
      #pragma unroll
      for (int nt=0;nt<4;++nt) o[1][nt] = MFMA(pa1, vf[nt], o[1][nt]);
      __builtin_amdgcn_s_setprio(0);
    }
  }

  // epilogue: deferred row-sum reduce, normalize, write
  #pragma unroll
  for (int sub=0;sub<2;++sub)
    #pragma unroll
    for (int j=0;j<4;++j){
      float s = lr[sub][j];
      s += __shfl_xor(s,1); s += __shfl_xor(s,2);
      s += __shfl_xor(s,4); s += __shfl_xor(s,8);
      const float inv = 1.f / fmaxf(s, 1e-30f);
      const int row = (qt<<7) + (wv<<5) + (sub<<4) + ((lane>>4)<<2) + j;
      u16* crow = ctx + ((size_t)((b<<10)+row))*1024 + hc;
      #pragma unroll
      for (int nt=0;nt<4;++nt)
        crow[(nt<<4)+l15] = f2bf(o[sub][nt][j]*inv);
    }
}

extern "C" void kernel_launch(void* const* d_in, const int* in_sizes, int n_in,
                              void* d_out, int out_size, void* d_ws, size_t ws_size,
                              hipStream_t stream) {
  const float* q    = (const float*)d_in[0];
  const float* k    = (const float*)d_in[1];
  const float* v    = (const float*)d_in[2];
  const int*   mask = (const int*)  d_in[3];
  const float* Wq   = (const float*)d_in[4];
  const float* bq   = (const float*)d_in[5];
  const float* Wk   = (const float*)d_in[6];
  const float* bk   = (const float*)d_in[7];
  const float* Wo   = (const float*)d_in[8];
  const float* bo   = (const float*)d_in[9];
  float* out = (float*)d_out;

  // ws layout: wqb 2M | wkb 2M | wob 2M | qb 8M | kb 8M | vb 8M | qp 8M | kp 8M
  //            | vt 8M | ctx 8M | gidx 16K | cnts
  char* ws = (char*)d_ws;
  u16* wqb  = (u16*)(ws);
  u16* wkb  = (u16*)(ws +  2097152);
  u16* wob  = (u16*)(ws +  4194304);
  u16* qb   = (u16*)(ws +  6291456);
  u16* kb   = (u16*)(ws + 14680064);
  u16* vb   = (u16*)(ws + 23068672);
  u16* qp   = (u16*)(ws + 31457280);
  u16* kp   = (u16*)(ws + 39845888);
  u16* vtb  = (u16*)(ws + 48234496);
  u16* ctxb = (u16*)(ws + 56623104);
  int* gidx = (int*)(ws + 65011712);
  int* cnts = (int*)(ws + 65028096);

  dim3 blk(256);
  prep_k<<<7684, blk, 0, stream>>>(Wq, Wk, Wo, q, k, v, wqb, mask, gidx, cnts);
  proj_k<<<768, blk, 0, stream>>>(qb, kb, vb, wqb, wkb, bq, bk, qp, kp, vtb, gidx, cnts);
  attn_k<<<512, blk, 0, stream>>>(qp, kp, vtb, cnts, ctxb);
  oproj_k<<<dim3(32,16), blk, 0, stream>>>(ctxb, wob, bo, out);
}